// Round 1
// baseline (1909.652 us; speedup 1.0000x reference)
//
#include <hip/hip_runtime.h>
#include <math.h>

#define S_LEN 2048
#define NHEADS 16
#define DK 64
#define BH (4 * NHEADS)

// ---------------- RoPE tables (double precision; 65536 threads, negligible) ----
__global__ void rope_table_kernel(const int* __restrict__ pos,
                                  float* __restrict__ sin_t,
                                  float* __restrict__ cos_t) {
  int idx = blockIdx.x * blockDim.x + threadIdx.x;
  if (idx >= S_LEN * 32) return;
  int s = idx >> 5, p = idx & 31;
  double inv = pow(10000.0, -(double)(2 * p) / 64.0);
  double a = (double)pos[s] * inv;
  sin_t[idx] = (float)sin(a);
  cos_t[idx] = (float)cos(a);
}

// ---------------- fp32 GEMM: C = A * B^T ---------------------------------------
// A: M x 1024 row-major; B: 1024 x 1024 row-major (N x K).
// mode 0: C[m*1024 + n]                       (final Wo projection)
// mode 1: C[((b*16+h)*2048+s)*64+d]           (V -> (B,H,S,D))
// mode 2: mode 1 + fused RoPE                 (Q, K)
__global__ __launch_bounds__(256) void gemm_nt_kernel(
    const float* __restrict__ A, const float* __restrict__ B,
    float* __restrict__ C, int M,
    const float* __restrict__ sin_t, const float* __restrict__ cos_t,
    int mode) {
  __shared__ float As[16][68];  // [k][m], pad 4 keeps 16B align + <=2-way banks
  __shared__ float Bs[16][68];  // [k][n]
  const int t  = threadIdx.x;
  const int tx = t & 15, ty = t >> 4;
  const int m0 = blockIdx.y * 64;
  const int n0 = blockIdx.x * 64;
  const int lr = t >> 2;          // 0..63 tile row
  const int lk = (t & 3) * 4;     // 0,4,8,12 k offset

  const float* Ag = A + (size_t)(m0 + lr) * 1024 + lk;
  const float* Bg = B + (size_t)(n0 + lr) * 1024 + lk;

  float acc[4][4] = {};
  for (int k0 = 0; k0 < 1024; k0 += 16) {
    float4 av = *(const float4*)(Ag + k0);
    float4 bv = *(const float4*)(Bg + k0);
    __syncthreads();
    As[lk + 0][lr] = av.x; As[lk + 1][lr] = av.y;
    As[lk + 2][lr] = av.z; As[lk + 3][lr] = av.w;
    Bs[lk + 0][lr] = bv.x; Bs[lk + 1][lr] = bv.y;
    Bs[lk + 2][lr] = bv.z; Bs[lk + 3][lr] = bv.w;
    __syncthreads();
#pragma unroll
    for (int kk = 0; kk < 16; kk++) {
      float4 a4 = *(const float4*)&As[kk][ty * 4];
      float4 b4 = *(const float4*)&Bs[kk][tx * 4];
      float a_[4] = {a4.x, a4.y, a4.z, a4.w};
      float b_[4] = {b4.x, b4.y, b4.z, b4.w};
#pragma unroll
      for (int i = 0; i < 4; i++)
#pragma unroll
        for (int j = 0; j < 4; j++)
          acc[i][j] += a_[i] * b_[j];
    }
  }

  if (mode == 0) {
#pragma unroll
    for (int i = 0; i < 4; i++) {
      float4 cv = make_float4(acc[i][0], acc[i][1], acc[i][2], acc[i][3]);
      *(float4*)&C[(size_t)(m0 + ty * 4 + i) * 1024 + n0 + tx * 4] = cv;
    }
  } else {
    const int h = n0 >> 6;  // tile width 64 == one head
#pragma unroll
    for (int i = 0; i < 4; i++) {
      int m = m0 + ty * 4 + i;
      int s = m & (S_LEN - 1);
      int b = m >> 11;
      float4 cv = make_float4(acc[i][0], acc[i][1], acc[i][2], acc[i][3]);
      if (mode == 2) {
        int p0 = 2 * tx;  // d = 4*tx + j -> pairs p0, p0+1
        float sn0 = sin_t[s * 32 + p0],     cs0 = cos_t[s * 32 + p0];
        float sn1 = sin_t[s * 32 + p0 + 1], cs1 = cos_t[s * 32 + p0 + 1];
        float e0 = cv.x, o0 = cv.y, e1 = cv.z, o1 = cv.w;
        cv.x = e0 * cs0 - o0 * sn0;
        cv.y = o0 * cs0 + e0 * sn0;
        cv.z = e1 * cs1 - o1 * sn1;
        cv.w = o1 * cs1 + e1 * sn1;
      }
      size_t off = (((size_t)b * NHEADS + h) * S_LEN + s) * DK + tx * 4;
      *(float4*)&C[off] = cv;
    }
  }
}

// ---------------- causal flash attention (fp32) --------------------------------
// Q,K,V: (BH, S, 64). One block per (bh, 64-row q-tile). 256 threads, 4x4 micro.
// O written as (B, S, H*64) for the Wo GEMM.
__global__ __launch_bounds__(256) void attn_kernel(
    const float* __restrict__ Q, const float* __restrict__ K,
    const float* __restrict__ V, float* __restrict__ O) {
  __shared__ float Qs[64][68];    // [q_row][d], pad 4
  __shared__ float KP[64 * 68];   // phase 1: K^T as [d*64 + c]; phase 2: P as [r*68 + c]
  __shared__ float Vs[64][64];    // [c][d] (2-way banks = free)

  const int bh = blockIdx.x;
  const int qt = blockIdx.y;
  const int t  = threadIdx.x;
  const int tx = t & 15, ty = t >> 4;
  const size_t base = (size_t)bh * S_LEN * DK;

  // load + pre-scale Q tile
#pragma unroll
  for (int i = 0; i < 4; i++) {
    int idx = t + i * 256;
    int r = idx >> 4;
    int c4 = (idx & 15) * 4;
    float4 v = *(const float4*)&Q[base + (size_t)(qt * 64 + r) * DK + c4];
    Qs[r][c4 + 0] = v.x * 0.125f;
    Qs[r][c4 + 1] = v.y * 0.125f;
    Qs[r][c4 + 2] = v.z * 0.125f;
    Qs[r][c4 + 3] = v.w * 0.125f;
  }

  float o[4][4] = {};
  float m_i[4] = {-INFINITY, -INFINITY, -INFINITY, -INFINITY};
  float l_i[4] = {0.f, 0.f, 0.f, 0.f};

  for (int kt = 0; kt <= qt; kt++) {
    __syncthreads();  // prior PV reads of KP/Vs done
#pragma unroll
    for (int i = 0; i < 4; i++) {
      int idx = t + i * 256;
      int r = idx >> 4;           // kv row within tile
      int c4 = (idx & 15) * 4;    // d
      float4 kv = *(const float4*)&K[base + (size_t)(kt * 64 + r) * DK + c4];
      KP[(c4 + 0) * 64 + r] = kv.x;
      KP[(c4 + 1) * 64 + r] = kv.y;
      KP[(c4 + 2) * 64 + r] = kv.z;
      KP[(c4 + 3) * 64 + r] = kv.w;
      float4 vv = *(const float4*)&V[base + (size_t)(kt * 64 + r) * DK + c4];
      *(float4*)&Vs[r][c4] = vv;
    }
    __syncthreads();

    // scores: s[i][j] = sum_d Qs[4ty+i][d] * K[4tx+j][d]
    float s[4][4] = {};
    for (int d4 = 0; d4 < 64; d4 += 4) {
      float qa[4][4], kb[4][4];
#pragma unroll
      for (int i = 0; i < 4; i++) {
        float4 qv = *(const float4*)&Qs[ty * 4 + i][d4];
        qa[i][0] = qv.x; qa[i][1] = qv.y; qa[i][2] = qv.z; qa[i][3] = qv.w;
      }
#pragma unroll
      for (int dd = 0; dd < 4; dd++) {
        float4 kv = *(const float4*)&KP[(d4 + dd) * 64 + tx * 4];
        kb[dd][0] = kv.x; kb[dd][1] = kv.y; kb[dd][2] = kv.z; kb[dd][3] = kv.w;
      }
#pragma unroll
      for (int i = 0; i < 4; i++)
#pragma unroll
        for (int dd = 0; dd < 4; dd++)
#pragma unroll
          for (int j = 0; j < 4; j++)
            s[i][j] += qa[i][dd] * kb[dd][j];
    }

    if (kt == qt) {
#pragma unroll
      for (int i = 0; i < 4; i++)
#pragma unroll
        for (int j = 0; j < 4; j++)
          if (tx * 4 + j > ty * 4 + i) s[i][j] = -INFINITY;
    }

    // online softmax (row = 16 consecutive lanes, same wave)
#pragma unroll
    for (int i = 0; i < 4; i++) {
      float mx = fmaxf(fmaxf(s[i][0], s[i][1]), fmaxf(s[i][2], s[i][3]));
#pragma unroll
      for (int off = 1; off < 16; off <<= 1)
        mx = fmaxf(mx, __shfl_xor(mx, off));
      float mnew = fmaxf(m_i[i], mx);
      float alpha = __expf(m_i[i] - mnew);
      float sum = 0.f;
#pragma unroll
      for (int j = 0; j < 4; j++) {
        float p = __expf(s[i][j] - mnew);
        s[i][j] = p;
        sum += p;
      }
#pragma unroll
      for (int off = 1; off < 16; off <<= 1)
        sum += __shfl_xor(sum, off);
      m_i[i] = mnew;
      l_i[i] = l_i[i] * alpha + sum;
#pragma unroll
      for (int j = 0; j < 4; j++) o[i][j] *= alpha;
    }

    __syncthreads();  // all score-phase reads of KP done
#pragma unroll
    for (int i = 0; i < 4; i++) {
      float4 pv = make_float4(s[i][0], s[i][1], s[i][2], s[i][3]);
      *(float4*)&KP[(ty * 4 + i) * 68 + tx * 4] = pv;
    }
    __syncthreads();

    // PV: o[i][j] += sum_c P[4ty+i][c] * V[c][4tx+j]
    for (int c4 = 0; c4 < 64; c4 += 4) {
      float pa[4][4], vb[4][4];
#pragma unroll
      for (int i = 0; i < 4; i++) {
        float4 pv = *(const float4*)&KP[(ty * 4 + i) * 68 + c4];
        pa[i][0] = pv.x; pa[i][1] = pv.y; pa[i][2] = pv.z; pa[i][3] = pv.w;
      }
#pragma unroll
      for (int cc = 0; cc < 4; cc++) {
        float4 vv = *(const float4*)&Vs[c4 + cc][tx * 4];
        vb[cc][0] = vv.x; vb[cc][1] = vv.y; vb[cc][2] = vv.z; vb[cc][3] = vv.w;
      }
#pragma unroll
      for (int i = 0; i < 4; i++)
#pragma unroll
        for (int cc = 0; cc < 4; cc++)
#pragma unroll
          for (int j = 0; j < 4; j++)
            o[i][j] += pa[i][cc] * vb[cc][j];
    }
  }

  // normalize + write to (B, S, H*64)
  const int b = bh >> 4, h = bh & 15;
#pragma unroll
  for (int i = 0; i < 4; i++) {
    int sg = qt * 64 + ty * 4 + i;
    float inv = 1.0f / l_i[i];
    float4 ov = make_float4(o[i][0] * inv, o[i][1] * inv,
                            o[i][2] * inv, o[i][3] * inv);
    *(float4*)&O[(((size_t)b * S_LEN + sg) * NHEADS + h) * DK + tx * 4] = ov;
  }
}

extern "C" void kernel_launch(void* const* d_in, const int* in_sizes, int n_in,
                              void* d_out, int out_size, void* d_ws, size_t ws_size,
                              hipStream_t stream) {
  const float* x   = (const float*)d_in[0];
  const int*   pos = (const int*)d_in[1];
  const float* Wq  = (const float*)d_in[2];
  const float* Wk  = (const float*)d_in[3];
  const float* Wv  = (const float*)d_in[4];
  const float* Wo  = (const float*)d_in[5];
  float* out = (float*)d_out;

  const size_t NTOK = (size_t)4 * S_LEN;         // 8192
  float* q     = (float*)d_ws;                   // (B,H,S,64)
  float* k     = q  + NTOK * 1024;
  float* v     = k  + NTOK * 1024;
  float* ao    = v  + NTOK * 1024;               // (B,S,1024)
  float* sin_t = ao + NTOK * 1024;
  float* cos_t = sin_t + S_LEN * 32;
  (void)in_sizes; (void)n_in; (void)out_size; (void)ws_size;

  rope_table_kernel<<<(S_LEN * 32 + 255) / 256, 256, 0, stream>>>(pos, sin_t, cos_t);

  dim3 gg(16, 128);  // N/64, M/64
  gemm_nt_kernel<<<gg, 256, 0, stream>>>(x, Wq, q, (int)NTOK, sin_t, cos_t, 2);
  gemm_nt_kernel<<<gg, 256, 0, stream>>>(x, Wk, k, (int)NTOK, sin_t, cos_t, 2);
  gemm_nt_kernel<<<gg, 256, 0, stream>>>(x, Wv, v, (int)NTOK, nullptr, nullptr, 1);

  dim3 ag(BH, S_LEN / 64);
  attn_kernel<<<ag, 256, 0, stream>>>(q, k, v, ao);

  gemm_nt_kernel<<<gg, 256, 0, stream>>>(ao, Wo, out, (int)NTOK, nullptr, nullptr, 0);
}

// Round 2
// 782.431 us; speedup vs baseline: 2.4407x; 2.4407x over previous
//
#include <hip/hip_runtime.h>
#include <math.h>

#define S_LEN 2048
#define NHEADS 16
#define DK 64

typedef _Float16 h4 __attribute__((ext_vector_type(4)));
typedef _Float16 h8 __attribute__((ext_vector_type(8)));
typedef float f4 __attribute__((ext_vector_type(4)));

__device__ __forceinline__ void glds16(const void* g, void* l) {
  __builtin_amdgcn_global_load_lds(
      (const __attribute__((address_space(1))) unsigned int*)g,
      (__attribute__((address_space(3))) unsigned int*)l, 16, 0, 0);
}

// ---------------- RoPE tables (double precision) -------------------------------
__global__ void rope_table_kernel(const int* __restrict__ pos,
                                  float* __restrict__ sin_t,
                                  float* __restrict__ cos_t) {
  int idx = blockIdx.x * blockDim.x + threadIdx.x;
  if (idx >= S_LEN * 32) return;
  int s = idx >> 5, p = idx & 31;
  double inv = pow(10000.0, -(double)(2 * p) / 64.0);
  double a = (double)pos[s] * inv;
  sin_t[idx] = (float)sin(a);
  cos_t[idx] = (float)cos(a);
}

// ---------------- fp32 -> f16 conversions --------------------------------------
__global__ __launch_bounds__(256) void cvt_x_kernel(const float* __restrict__ src,
                                                    _Float16* __restrict__ dst) {
  int i = blockIdx.x * 256 + threadIdx.x;  // 2M threads, float4 each
  float4 v = *(const float4*)(src + (size_t)i * 4);
  h4 o = {(_Float16)v.x, (_Float16)v.y, (_Float16)v.z, (_Float16)v.w};
  *(h4*)&dst[(size_t)i * 4] = o;
}

__global__ __launch_bounds__(256) void cvt_w_kernel(
    const float* __restrict__ w0, const float* __restrict__ w1,
    const float* __restrict__ w2, const float* __restrict__ w3,
    _Float16* __restrict__ dst) {
  int i = blockIdx.x * 256 + threadIdx.x;  // 1M threads, float4 each
  const float* srcs[4] = {w0, w1, w2, w3};
  int which = i >> 18;                     // 262144 float4 per matrix
  int off = (i & 262143) * 4;
  float4 v = *(const float4*)(srcs[which] + off);
  // scale by 256 (exact pow2) to keep all weight magnitudes in f16 normal range
  h4 o = {(_Float16)(v.x * 256.f), (_Float16)(v.y * 256.f),
          (_Float16)(v.z * 256.f), (_Float16)(v.w * 256.f)};
  *(h4*)&dst[(size_t)which * 1048576 + off] = o;
}

// ---------------- f16 MFMA GEMM: C = A * B^T  (K = 1024) -----------------------
// A: M x 1024 f16 row-major; B: 1024 x 1024 f16 row-major (N x K), pre-scaled x256.
// mode 0: C32[m*1024+n]         mode 1: C16[((b*16+h)*2048+s)*64+d]
// mode 2: mode 1 + fused RoPE
__global__ __launch_bounds__(256) void gemm_f16_nt(
    const _Float16* __restrict__ A, const _Float16* __restrict__ B,
    float* __restrict__ C32, _Float16* __restrict__ C16,
    const float* __restrict__ sin_t, const float* __restrict__ cos_t,
    int mode) {
  __shared__ _Float16 As[128 * 32];
  __shared__ _Float16 Bs[128 * 32];
  const int t = threadIdx.x;
  const int lane = t & 63;
  const int w = t >> 6;                 // wave 0..3
  const int m0 = blockIdx.y * 128;
  const int n0 = blockIdx.x * 128;
  const int wm = (w >> 1) * 64;         // wave's 64x64 sub-tile
  const int wn = (w & 1) * 64;
  const int lm = lane & 15;             // row/col within 16x16 MFMA tile
  const int kq = (lane >> 4) * 8;       // k offset within 32-chunk (A-frag layout)
  const int srow = lane >> 2;           // staging: row within 16-row chunk
  const int skof = (lane & 3) * 8;      // staging: k elems within row

  f4 acc[4][4];
#pragma unroll
  for (int i = 0; i < 4; i++)
#pragma unroll
    for (int j = 0; j < 4; j++) {
      f4 z = {0.f, 0.f, 0.f, 0.f};
      acc[i][j] = z;
    }

  for (int k0 = 0; k0 < 1024; k0 += 32) {
    __syncthreads();  // prior chunk's frag reads done
#pragma unroll
    for (int c = 0; c < 2; c++) {
      int rr = (w + c * 4) * 16 + srow;  // 0..127
      glds16(A + (size_t)(m0 + rr) * 1024 + k0 + skof, (char*)As + (w + c * 4) * 1024);
      glds16(B + (size_t)(n0 + rr) * 1024 + k0 + skof, (char*)Bs + (w + c * 4) * 1024);
    }
    __syncthreads();  // staging visible (drains vmcnt)

    h8 af[4], bf[4];
#pragma unroll
    for (int mt = 0; mt < 4; mt++)
      af[mt] = *(const h8*)(As + (wm + mt * 16 + lm) * 32 + kq);
#pragma unroll
    for (int nt = 0; nt < 4; nt++)
      bf[nt] = *(const h8*)(Bs + (wn + nt * 16 + lm) * 32 + kq);
#pragma unroll
    for (int mt = 0; mt < 4; mt++)
#pragma unroll
      for (int nt = 0; nt < 4; nt++)
        acc[mt][nt] = __builtin_amdgcn_mfma_f32_16x16x32_f16(af[mt], bf[nt],
                                                             acc[mt][nt], 0, 0, 0);
  }

  // epilogue: scale 1/256 (undo weight scaling); C/D layout: n=lane&15, m=quad*4+reg
  const float scale = 1.0f / 256.0f;
  const int qrow = lane >> 4;
#pragma unroll
  for (int mt = 0; mt < 4; mt++) {
#pragma unroll
    for (int nt = 0; nt < 4; nt++) {
      int n = n0 + wn + nt * 16 + lm;
#pragma unroll
      for (int r = 0; r < 4; r++) {
        int m = m0 + wm + mt * 16 + qrow * 4 + r;
        float v = acc[mt][nt][r] * scale;
        if (mode == 0) {
          C32[(size_t)m * 1024 + n] = v;
        } else {
          int s = m & (S_LEN - 1), b = m >> 11;
          int d = n & 63, h = n >> 6;
          if (mode == 2) {
            // even/odd d pair lives in adjacent lanes (n differs in bit 0)
            float partner = __shfl_xor(v, 1);
            int p = d >> 1;
            float sn = sin_t[s * 32 + p], cs = cos_t[s * 32 + p];
            v = (d & 1) ? (v * cs + partner * sn) : (v * cs - partner * sn);
          }
          C16[(((size_t)b * NHEADS + h) * S_LEN + s) * DK + d] = (_Float16)v;
        }
      }
    }
  }
}

// ---------------- causal flash attention (fp32 compute, f16 I/O) ---------------
// Q,K,V: (B*H, S, 64) f16. One block per (bh, 64-row q-tile). 256 threads, 4x4.
// O written f16 as (B, S, H*64) for the Wo GEMM.
__global__ __launch_bounds__(256) void attn_kernel(
    const _Float16* __restrict__ Q, const _Float16* __restrict__ K,
    const _Float16* __restrict__ V, _Float16* __restrict__ O) {
  __shared__ float Qs[64][68];    // [q_row][d], pad 4
  __shared__ float KP[64 * 68];   // phase 1: K^T as [d*64 + c]; phase 2: P as [r*68 + c]
  __shared__ float Vs[64][64];    // [c][d]

  const int bh = blockIdx.x;
  const int qt = blockIdx.y;
  const int t  = threadIdx.x;
  const int tx = t & 15, ty = t >> 4;
  const size_t base = (size_t)bh * S_LEN * DK;

  // load + pre-scale Q tile (1/sqrt(64) = 0.125)
#pragma unroll
  for (int i = 0; i < 2; i++) {
    int idx = t + i * 256;
    int r = idx >> 3;
    int c8 = (idx & 7) * 8;
    h8 v = *(const h8*)&Q[base + (size_t)(qt * 64 + r) * DK + c8];
#pragma unroll
    for (int j = 0; j < 8; j++) Qs[r][c8 + j] = (float)v[j] * 0.125f;
  }

  float o[4][4] = {};
  float m_i[4] = {-INFINITY, -INFINITY, -INFINITY, -INFINITY};
  float l_i[4] = {0.f, 0.f, 0.f, 0.f};

  for (int kt = 0; kt <= qt; kt++) {
    __syncthreads();  // prior PV reads of KP/Vs done
#pragma unroll
    for (int i = 0; i < 2; i++) {
      int idx = t + i * 256;
      int r = idx >> 3;
      int c8 = (idx & 7) * 8;
      h8 kv = *(const h8*)&K[base + (size_t)(kt * 64 + r) * DK + c8];
#pragma unroll
      for (int j = 0; j < 8; j++) KP[(c8 + j) * 64 + r] = (float)kv[j];
      h8 vv = *(const h8*)&V[base + (size_t)(kt * 64 + r) * DK + c8];
#pragma unroll
      for (int j = 0; j < 8; j++) Vs[r][c8 + j] = (float)vv[j];
    }
    __syncthreads();

    // scores: s[i][j] = sum_d Qs[4ty+i][d] * K[4tx+j][d]
    float s[4][4] = {};
    for (int d4 = 0; d4 < 64; d4 += 4) {
      float qa[4][4], kb[4][4];
#pragma unroll
      for (int i = 0; i < 4; i++) {
        float4 qv = *(const float4*)&Qs[ty * 4 + i][d4];
        qa[i][0] = qv.x; qa[i][1] = qv.y; qa[i][2] = qv.z; qa[i][3] = qv.w;
      }
#pragma unroll
      for (int dd = 0; dd < 4; dd++) {
        float4 kv = *(const float4*)&KP[(d4 + dd) * 64 + tx * 4];
        kb[dd][0] = kv.x; kb[dd][1] = kv.y; kb[dd][2] = kv.z; kb[dd][3] = kv.w;
      }
#pragma unroll
      for (int i = 0; i < 4; i++)
#pragma unroll
        for (int dd = 0; dd < 4; dd++)
#pragma unroll
          for (int j = 0; j < 4; j++)
            s[i][j] += qa[i][dd] * kb[dd][j];
    }

    if (kt == qt) {
#pragma unroll
      for (int i = 0; i < 4; i++)
#pragma unroll
        for (int j = 0; j < 4; j++)
          if (tx * 4 + j > ty * 4 + i) s[i][j] = -INFINITY;
    }

    // online softmax (row = 16 consecutive lanes, same wave)
#pragma unroll
    for (int i = 0; i < 4; i++) {
      float mx = fmaxf(fmaxf(s[i][0], s[i][1]), fmaxf(s[i][2], s[i][3]));
#pragma unroll
      for (int off = 1; off < 16; off <<= 1)
        mx = fmaxf(mx, __shfl_xor(mx, off));
      float mnew = fmaxf(m_i[i], mx);
      float alpha = __expf(m_i[i] - mnew);
      float sum = 0.f;
#pragma unroll
      for (int j = 0; j < 4; j++) {
        float p = __expf(s[i][j] - mnew);
        s[i][j] = p;
        sum += p;
      }
#pragma unroll
      for (int off = 1; off < 16; off <<= 1)
        sum += __shfl_xor(sum, off);
      m_i[i] = mnew;
      l_i[i] = l_i[i] * alpha + sum;
#pragma unroll
      for (int j = 0; j < 4; j++) o[i][j] *= alpha;
    }

    __syncthreads();  // all score-phase reads of KP done
#pragma unroll
    for (int i = 0; i < 4; i++) {
      float4 pv = make_float4(s[i][0], s[i][1], s[i][2], s[i][3]);
      *(float4*)&KP[(ty * 4 + i) * 68 + tx * 4] = pv;
    }
    __syncthreads();

    // PV: o[i][j] += sum_c P[4ty+i][c] * V[c][4tx+j]
    for (int c4 = 0; c4 < 64; c4 += 4) {
      float pa[4][4], vb[4][4];
#pragma unroll
      for (int i = 0; i < 4; i++) {
        float4 pv = *(const float4*)&KP[(ty * 4 + i) * 68 + c4];
        pa[i][0] = pv.x; pa[i][1] = pv.y; pa[i][2] = pv.z; pa[i][3] = pv.w;
      }
#pragma unroll
      for (int cc = 0; cc < 4; cc++) {
        float4 vv = *(const float4*)&Vs[c4 + cc][tx * 4];
        vb[cc][0] = vv.x; vb[cc][1] = vv.y; vb[cc][2] = vv.z; vb[cc][3] = vv.w;
      }
#pragma unroll
      for (int i = 0; i < 4; i++)
#pragma unroll
        for (int cc = 0; cc < 4; cc++)
#pragma unroll
          for (int j = 0; j < 4; j++)
            o[i][j] += pa[i][cc] * vb[cc][j];
    }
  }

  // normalize + write f16 to (B, S, H*64)
  const int b = bh >> 4, h = bh & 15;
#pragma unroll
  for (int i = 0; i < 4; i++) {
    int sg = qt * 64 + ty * 4 + i;
    float inv = 1.0f / l_i[i];
    h4 ov = {(_Float16)(o[i][0] * inv), (_Float16)(o[i][1] * inv),
             (_Float16)(o[i][2] * inv), (_Float16)(o[i][3] * inv)};
    *(h4*)&O[(((size_t)b * S_LEN + sg) * NHEADS + h) * DK + tx * 4] = ov;
  }
}

extern "C" void kernel_launch(void* const* d_in, const int* in_sizes, int n_in,
                              void* d_out, int out_size, void* d_ws, size_t ws_size,
                              hipStream_t stream) {
  const float* x   = (const float*)d_in[0];
  const int*   pos = (const int*)d_in[1];
  const float* Wq  = (const float*)d_in[2];
  const float* Wk  = (const float*)d_in[3];
  const float* Wv  = (const float*)d_in[4];
  const float* Wo  = (const float*)d_in[5];
  float* out = (float*)d_out;
  (void)in_sizes; (void)n_in; (void)out_size; (void)ws_size;

  const size_t NT = (size_t)4 * S_LEN * 1024;  // 8.39M elements
  _Float16* q16 = (_Float16*)d_ws;
  _Float16* k16 = q16 + NT;
  _Float16* v16 = k16 + NT;
  _Float16* aoh = v16 + NT;
  _Float16* xh  = aoh + NT;
  _Float16* wh  = xh + NT;                     // 4 x 1048576
  float* sin_t = (float*)(wh + 4 * 1048576);
  float* cos_t = sin_t + S_LEN * 32;

  rope_table_kernel<<<(S_LEN * 32 + 255) / 256, 256, 0, stream>>>(pos, sin_t, cos_t);
  cvt_x_kernel<<<8192, 256, 0, stream>>>(x, xh);
  cvt_w_kernel<<<4096, 256, 0, stream>>>(Wq, Wk, Wv, Wo, wh);

  dim3 gg(8, 64);  // N/128, M/128
  gemm_f16_nt<<<gg, 256, 0, stream>>>(xh, wh,           nullptr, q16, sin_t, cos_t, 2);
  gemm_f16_nt<<<gg, 256, 0, stream>>>(xh, wh + 1048576, nullptr, k16, sin_t, cos_t, 2);
  gemm_f16_nt<<<gg, 256, 0, stream>>>(xh, wh + 2097152, nullptr, v16, nullptr, nullptr, 1);

  dim3 ag(64, S_LEN / 64);
  attn_kernel<<<ag, 256, 0, stream>>>(q16, k16, v16, aoh);

  gemm_f16_nt<<<gg, 256, 0, stream>>>(aoh, wh + 3145728, out, nullptr, nullptr, nullptr, 0);
}

// Round 3
// 319.350 us; speedup vs baseline: 5.9798x; 2.4501x over previous
//
#include <hip/hip_runtime.h>
#include <math.h>

#define S_LEN 2048
#define NHEADS 16
#define DK 64

typedef _Float16 h4 __attribute__((ext_vector_type(4)));
typedef _Float16 h8 __attribute__((ext_vector_type(8)));
typedef float f4 __attribute__((ext_vector_type(4)));

__device__ __forceinline__ void glds16(const void* g, void* l) {
  __builtin_amdgcn_global_load_lds(
      (const __attribute__((address_space(1))) unsigned int*)g,
      (__attribute__((address_space(3))) unsigned int*)l, 16, 0, 0);
}

// ---------------- RoPE tables (double precision) -------------------------------
__global__ void rope_table_kernel(const int* __restrict__ pos,
                                  float* __restrict__ sin_t,
                                  float* __restrict__ cos_t) {
  int idx = blockIdx.x * blockDim.x + threadIdx.x;
  if (idx >= S_LEN * 32) return;
  int s = idx >> 5, p = idx & 31;
  double inv = pow(10000.0, -(double)(2 * p) / 64.0);
  double a = (double)pos[s] * inv;
  sin_t[idx] = (float)sin(a);
  cos_t[idx] = (float)cos(a);
}

// ---------------- fp32 -> f16 conversions --------------------------------------
__global__ __launch_bounds__(256) void cvt_x_kernel(const float* __restrict__ src,
                                                    _Float16* __restrict__ dst) {
  int i = blockIdx.x * 256 + threadIdx.x;
  float4 v = *(const float4*)(src + (size_t)i * 4);
  h4 o = {(_Float16)v.x, (_Float16)v.y, (_Float16)v.z, (_Float16)v.w};
  *(h4*)&dst[(size_t)i * 4] = o;
}

__global__ __launch_bounds__(256) void cvt_w_kernel(
    const float* __restrict__ w0, const float* __restrict__ w1,
    const float* __restrict__ w2, const float* __restrict__ w3,
    _Float16* __restrict__ dst) {
  int i = blockIdx.x * 256 + threadIdx.x;
  const float* srcs[4] = {w0, w1, w2, w3};
  int which = i >> 18;
  int off = (i & 262143) * 4;
  float4 v = *(const float4*)(srcs[which] + off);
  h4 o = {(_Float16)(v.x * 256.f), (_Float16)(v.y * 256.f),
          (_Float16)(v.z * 256.f), (_Float16)(v.w * 256.f)};
  *(h4*)&dst[(size_t)which * 1048576 + off] = o;
}

// ---------------- f16 MFMA GEMM: C = A * B^T  (K = 1024) -----------------------
// mode 0: C32[m*1024+n]
// mode 1: V -> transposed Vt[((b*16+h)*64+d)*2048+s]
// mode 2: Q/K -> C16[((b*16+h)*2048+s)*64+d] + fused RoPE
__global__ __launch_bounds__(256) void gemm_f16_nt(
    const _Float16* __restrict__ A, const _Float16* __restrict__ B,
    float* __restrict__ C32, _Float16* __restrict__ C16,
    const float* __restrict__ sin_t, const float* __restrict__ cos_t,
    int mode) {
  __shared__ _Float16 As[128 * 32];
  __shared__ _Float16 Bs[128 * 32];
  const int t = threadIdx.x;
  const int lane = t & 63;
  const int w = t >> 6;
  const int m0 = blockIdx.y * 128;
  const int n0 = blockIdx.x * 128;
  const int wm = (w >> 1) * 64;
  const int wn = (w & 1) * 64;
  const int lm = lane & 15;
  const int kq = (lane >> 4) * 8;
  const int srow = lane >> 2;
  const int skof = (lane & 3) * 8;

  f4 acc[4][4];
#pragma unroll
  for (int i = 0; i < 4; i++)
#pragma unroll
    for (int j = 0; j < 4; j++) {
      f4 z = {0.f, 0.f, 0.f, 0.f};
      acc[i][j] = z;
    }

  for (int k0 = 0; k0 < 1024; k0 += 32) {
    __syncthreads();
#pragma unroll
    for (int c = 0; c < 2; c++) {
      int rr = (w + c * 4) * 16 + srow;
      glds16(A + (size_t)(m0 + rr) * 1024 + k0 + skof, (char*)As + (w + c * 4) * 1024);
      glds16(B + (size_t)(n0 + rr) * 1024 + k0 + skof, (char*)Bs + (w + c * 4) * 1024);
    }
    __syncthreads();

    h8 af[4], bf[4];
#pragma unroll
    for (int mt = 0; mt < 4; mt++)
      af[mt] = *(const h8*)(As + (wm + mt * 16 + lm) * 32 + kq);
#pragma unroll
    for (int nt = 0; nt < 4; nt++)
      bf[nt] = *(const h8*)(Bs + (wn + nt * 16 + lm) * 32 + kq);
#pragma unroll
    for (int mt = 0; mt < 4; mt++)
#pragma unroll
      for (int nt = 0; nt < 4; nt++)
        acc[mt][nt] = __builtin_amdgcn_mfma_f32_16x16x32_f16(af[mt], bf[nt],
                                                             acc[mt][nt], 0, 0, 0);
  }

  const float scale = 1.0f / 256.0f;
  const int qrow = lane >> 4;
#pragma unroll
  for (int mt = 0; mt < 4; mt++) {
#pragma unroll
    for (int nt = 0; nt < 4; nt++) {
      int n = n0 + wn + nt * 16 + lm;
      if (mode == 1) {
        int d = n & 63, h = n >> 6;
        int mbase = m0 + wm + mt * 16 + qrow * 4;
        int s = mbase & (S_LEN - 1), b = mbase >> 11;
        h4 ov = {(_Float16)(acc[mt][nt][0] * scale), (_Float16)(acc[mt][nt][1] * scale),
                 (_Float16)(acc[mt][nt][2] * scale), (_Float16)(acc[mt][nt][3] * scale)};
        *(h4*)&C16[(((size_t)b * NHEADS + h) * DK + d) * S_LEN + s] = ov;
      } else {
#pragma unroll
        for (int r = 0; r < 4; r++) {
          int m = m0 + wm + mt * 16 + qrow * 4 + r;
          float v = acc[mt][nt][r] * scale;
          if (mode == 0) {
            C32[(size_t)m * 1024 + n] = v;
          } else {
            int s = m & (S_LEN - 1), b = m >> 11;
            int d = n & 63, h = n >> 6;
            float partner = __shfl_xor(v, 1);
            int p = d >> 1;
            float sn = sin_t[s * 32 + p], cs = cos_t[s * 32 + p];
            v = (d & 1) ? (v * cs + partner * sn) : (v * cs - partner * sn);
            C16[(((size_t)b * NHEADS + h) * S_LEN + s) * DK + d] = (_Float16)v;
          }
        }
      }
    }
  }
}

// ---------------- MFMA causal flash attention ----------------------------------
// Q,K: (B*H, S, 64) f16.  Vt: (B*H, 64, S) f16.  O: (B, S, H*64) f16.
// Block: 256 thr = 4 waves; Q-tile 128 (wave owns 32 q-rows); KV-step 64.
// S^T = mfma(Kfrag, Qfrag): C/D col = s_q (lane&15), rows = c -> softmax
// needs only shfl_xor(16,32); P written as h4; O^T = mfma(Vtfrag, Pfrag).
__global__ __launch_bounds__(256) void attn_mfma(
    const _Float16* __restrict__ Q, const _Float16* __restrict__ K,
    const _Float16* __restrict__ Vt, _Float16* __restrict__ O) {
  __shared__ _Float16 Ks[64 * 72];   // [s_k][d] stride 72
  __shared__ _Float16 Vs[64 * 72];   // [d][c]  stride 72
  __shared__ _Float16 Ps[128 * 72];  // [s_q][c] stride 72

  const int bh = blockIdx.x;
  const int qt = (gridDim.y - 1) - blockIdx.y;  // heavy tiles dispatch first
  const int q0 = qt * 128;
  const int t = threadIdx.x;
  const int lane = t & 63;
  const int w = t >> 6;
  const int lm = lane & 15;
  const int quad = lane >> 4;
  const size_t qkbase = (size_t)bh * S_LEN * DK;  // Q,K: (s,d)
  const size_t vbase  = (size_t)bh * DK * S_LEN;  // Vt: (d,s)

  // staging assignment: thread covers 32 contiguous bytes of one row
  const int srow = t >> 2;          // 0..63
  const int scol = (t & 3) * 16;    // 0,16,32,48

  // Q fragments in registers, pre-scaled by 1/sqrt(64)=0.125 (exact in f16)
  h8 qf[2][2];
#pragma unroll
  for (int nt = 0; nt < 2; nt++)
#pragma unroll
    for (int kc = 0; kc < 2; kc++) {
      h8 v = *(const h8*)(Q + qkbase + (size_t)(q0 + w * 32 + nt * 16 + lm) * DK +
                          kc * 32 + quad * 8);
#pragma unroll
      for (int j = 0; j < 8; j++) v[j] = v[j] * (_Float16)0.125f;
      qf[nt][kc] = v;
    }

  f4 oacc[4][2];
#pragma unroll
  for (int mt = 0; mt < 4; mt++)
#pragma unroll
    for (int nt = 0; nt < 2; nt++) {
      f4 z = {0.f, 0.f, 0.f, 0.f};
      oacc[mt][nt] = z;
    }
  float m_i[2] = {-INFINITY, -INFINITY};
  float l_i[2] = {0.f, 0.f};

  const int ktmax = (q0 >> 6) + 1;
  for (int kt = 0; kt <= ktmax; kt++) {
    __syncthreads();  // prior step's frag reads done
    {
      const _Float16* kg = K + qkbase + (size_t)(kt * 64 + srow) * DK + scol;
      const _Float16* vg = Vt + vbase + (size_t)srow * S_LEN + kt * 64 + scol;
      h8 k0 = *(const h8*)kg;
      h8 k1 = *(const h8*)(kg + 8);
      h8 v0 = *(const h8*)vg;
      h8 v1 = *(const h8*)(vg + 8);
      *(h8*)&Ks[srow * 72 + scol] = k0;
      *(h8*)&Ks[srow * 72 + scol + 8] = k1;
      *(h8*)&Vs[srow * 72 + scol] = v0;
      *(h8*)&Vs[srow * 72 + scol + 8] = v1;
    }
    __syncthreads();  // staging visible

    // S^T[c][s_q]: 4 c-tiles x 2 q-tiles
    f4 s_[4][2];
#pragma unroll
    for (int mt = 0; mt < 4; mt++)
#pragma unroll
      for (int nt = 0; nt < 2; nt++) {
        f4 z = {0.f, 0.f, 0.f, 0.f};
        s_[mt][nt] = z;
      }
#pragma unroll
    for (int kc = 0; kc < 2; kc++) {
      h8 kf[4];
#pragma unroll
      for (int mt = 0; mt < 4; mt++)
        kf[mt] = *(const h8*)&Ks[(mt * 16 + lm) * 72 + kc * 32 + quad * 8];
#pragma unroll
      for (int mt = 0; mt < 4; mt++)
#pragma unroll
        for (int nt = 0; nt < 2; nt++)
          s_[mt][nt] = __builtin_amdgcn_mfma_f32_16x16x32_f16(kf[mt], qf[nt][kc],
                                                              s_[mt][nt], 0, 0, 0);
    }

    // causal mask (diagonal steps only; wave-uniform branch)
    if (kt * 64 + 63 > q0 + w * 32) {
#pragma unroll
      for (int nt = 0; nt < 2; nt++) {
        int srq = q0 + w * 32 + nt * 16 + lm;
#pragma unroll
        for (int mt = 0; mt < 4; mt++)
#pragma unroll
          for (int r = 0; r < 4; r++)
            if (kt * 64 + mt * 16 + quad * 4 + r > srq) s_[mt][nt][r] = -INFINITY;
      }
    }

    // online softmax; P -> LDS as f16 h4
#pragma unroll
    for (int nt = 0; nt < 2; nt++) {
      float mx = -INFINITY;
#pragma unroll
      for (int mt = 0; mt < 4; mt++)
#pragma unroll
        for (int r = 0; r < 4; r++) mx = fmaxf(mx, s_[mt][nt][r]);
      mx = fmaxf(mx, __shfl_xor(mx, 16));
      mx = fmaxf(mx, __shfl_xor(mx, 32));
      float mnew = fmaxf(m_i[nt], mx);
      float alpha = __expf(m_i[nt] - mnew);
      float sum = 0.f;
#pragma unroll
      for (int mt = 0; mt < 4; mt++) {
#pragma unroll
        for (int r = 0; r < 4; r++) {
          float p = __expf(s_[mt][nt][r] - mnew);
          s_[mt][nt][r] = p;
          sum += p;
        }
      }
      sum += __shfl_xor(sum, 16);
      sum += __shfl_xor(sum, 32);
      m_i[nt] = mnew;
      l_i[nt] = l_i[nt] * alpha + sum;
#pragma unroll
      for (int mt = 0; mt < 4; mt++) {
        oacc[mt][nt][0] *= alpha; oacc[mt][nt][1] *= alpha;
        oacc[mt][nt][2] *= alpha; oacc[mt][nt][3] *= alpha;
        h4 pv = {(_Float16)s_[mt][nt][0], (_Float16)s_[mt][nt][1],
                 (_Float16)s_[mt][nt][2], (_Float16)s_[mt][nt][3]};
        *(h4*)&Ps[(w * 32 + nt * 16 + lm) * 72 + mt * 16 + quad * 4] = pv;
      }
    }
    __syncthreads();  // P visible

    // O^T += Vt_tile * P^T : 4 d-tiles x 2 q-tiles
#pragma unroll
    for (int kc = 0; kc < 2; kc++) {
      h8 vf[4], pf[2];
#pragma unroll
      for (int mt = 0; mt < 4; mt++)
        vf[mt] = *(const h8*)&Vs[(mt * 16 + lm) * 72 + kc * 32 + quad * 8];
#pragma unroll
      for (int nt = 0; nt < 2; nt++)
        pf[nt] = *(const h8*)&Ps[(w * 32 + nt * 16 + lm) * 72 + kc * 32 + quad * 8];
#pragma unroll
      for (int mt = 0; mt < 4; mt++)
#pragma unroll
        for (int nt = 0; nt < 2; nt++)
          oacc[mt][nt] = __builtin_amdgcn_mfma_f32_16x16x32_f16(vf[mt], pf[nt],
                                                                oacc[mt][nt], 0, 0, 0);
    }
  }

  // normalize + store O^T tiles: col = s_q (lane), rows = 4 consecutive d -> h4
  const int b = bh >> 4, head = bh & 15;
#pragma unroll
  for (int nt = 0; nt < 2; nt++) {
    float inv = 1.0f / l_i[nt];
    int s = q0 + w * 32 + nt * 16 + lm;
#pragma unroll
    for (int mt = 0; mt < 4; mt++) {
      h4 ov = {(_Float16)(oacc[mt][nt][0] * inv), (_Float16)(oacc[mt][nt][1] * inv),
               (_Float16)(oacc[mt][nt][2] * inv), (_Float16)(oacc[mt][nt][3] * inv)};
      *(h4*)&O[((size_t)b * S_LEN + s) * 1024 + head * 64 + mt * 16 + quad * 4] = ov;
    }
  }
}

extern "C" void kernel_launch(void* const* d_in, const int* in_sizes, int n_in,
                              void* d_out, int out_size, void* d_ws, size_t ws_size,
                              hipStream_t stream) {
  const float* x   = (const float*)d_in[0];
  const int*   pos = (const int*)d_in[1];
  const float* Wq  = (const float*)d_in[2];
  const float* Wk  = (const float*)d_in[3];
  const float* Wv  = (const float*)d_in[4];
  const float* Wo  = (const float*)d_in[5];
  float* out = (float*)d_out;
  (void)in_sizes; (void)n_in; (void)out_size; (void)ws_size;

  const size_t NT = (size_t)4 * S_LEN * 1024;
  _Float16* q16 = (_Float16*)d_ws;
  _Float16* k16 = q16 + NT;
  _Float16* vt16 = k16 + NT;
  _Float16* aoh = vt16 + NT;
  _Float16* xh  = aoh + NT;
  _Float16* wh  = xh + NT;
  float* sin_t = (float*)(wh + 4 * 1048576);
  float* cos_t = sin_t + S_LEN * 32;

  rope_table_kernel<<<(S_LEN * 32 + 255) / 256, 256, 0, stream>>>(pos, sin_t, cos_t);
  cvt_x_kernel<<<8192, 256, 0, stream>>>(x, xh);
  cvt_w_kernel<<<4096, 256, 0, stream>>>(Wq, Wk, Wv, Wo, wh);

  dim3 gg(8, 64);
  gemm_f16_nt<<<gg, 256, 0, stream>>>(xh, wh,           nullptr, q16, sin_t, cos_t, 2);
  gemm_f16_nt<<<gg, 256, 0, stream>>>(xh, wh + 1048576, nullptr, k16, sin_t, cos_t, 2);
  gemm_f16_nt<<<gg, 256, 0, stream>>>(xh, wh + 2097152, nullptr, vt16, nullptr, nullptr, 1);

  dim3 ag(64, S_LEN / 128);
  attn_mfma<<<ag, 256, 0, stream>>>(q16, k16, vt16, aoh);

  gemm_f16_nt<<<gg, 256, 0, stream>>>(aoh, wh + 3145728, out, nullptr, nullptr, nullptr, 0);
}

// Round 5
// 277.378 us; speedup vs baseline: 6.8846x; 1.1513x over previous
//
#include <hip/hip_runtime.h>
#include <math.h>

#define S_LEN 2048
#define NHEADS 16
#define DK 64

typedef _Float16 h4 __attribute__((ext_vector_type(4)));
typedef _Float16 h8 __attribute__((ext_vector_type(8)));
typedef float f4 __attribute__((ext_vector_type(4)));

__device__ __forceinline__ void glds16(const void* g, void* l) {
  __builtin_amdgcn_global_load_lds(
      (const __attribute__((address_space(1))) unsigned int*)g,
      (__attribute__((address_space(3))) unsigned int*)l, 16, 0, 0);
}

// ---------------- RoPE table, interleaved {sin,cos} (double precision) ---------
__global__ void rope_table_kernel(const int* __restrict__ pos,
                                  float* __restrict__ sc) {
  int idx = blockIdx.x * blockDim.x + threadIdx.x;
  if (idx >= S_LEN * 32) return;
  int s = idx >> 5, p = idx & 31;
  double inv = pow(10000.0, -(double)(2 * p) / 64.0);
  double a = (double)pos[s] * inv;
  sc[s * 64 + 2 * p]     = (float)sin(a);
  sc[s * 64 + 2 * p + 1] = (float)cos(a);
}

// ---------------- fp32 -> f16 conversions (x + 4 weights, one kernel) ----------
__global__ __launch_bounds__(256) void cvt_all(
    const float* __restrict__ x,
    const float* __restrict__ w0, const float* __restrict__ w1,
    const float* __restrict__ w2, const float* __restrict__ w3,
    _Float16* __restrict__ xh, _Float16* __restrict__ wh) {
  int bid = blockIdx.x;
  if (bid < 8192) {
    int i = bid * 256 + threadIdx.x;
    float4 v = *(const float4*)(x + (size_t)i * 4);
    h4 o = {(_Float16)v.x, (_Float16)v.y, (_Float16)v.z, (_Float16)v.w};
    *(h4*)&xh[(size_t)i * 4] = o;
  } else {
    int j = (bid - 8192) * 256 + threadIdx.x;
    const float* srcs[4] = {w0, w1, w2, w3};
    int which = j >> 18;
    int off = (j & 262143) * 4;
    float4 v = *(const float4*)(srcs[which] + off);
    // scale by 256 (exact pow2): keeps all weights in f16 normal range
    h4 o = {(_Float16)(v.x * 256.f), (_Float16)(v.y * 256.f),
            (_Float16)(v.z * 256.f), (_Float16)(v.w * 256.f)};
    *(h4*)&wh[(size_t)which * 1048576 + off] = o;
  }
}

// ---------------- fused QKV GEMM: {Q,K,V} = x * W^T  (K = 1024) ----------------
// grid (24, 64): blockIdx.x -> {matrix 0..2} x {n-tile 0..7}; 128x128 tiles.
// Q/K: rope epilogue -> (B*H, S, 64); V: transposed -> (B*H, 64, S).
__global__ __launch_bounds__(256) void gemm_qkv(
    const _Float16* __restrict__ A, const _Float16* __restrict__ W3,
    _Float16* __restrict__ Qo, _Float16* __restrict__ Ko,
    _Float16* __restrict__ Vto, const float* __restrict__ sc_t) {
  __shared__ _Float16 As[128 * 32];
  __shared__ _Float16 Bs[128 * 32];
  const int t = threadIdx.x;
  const int lane = t & 63;
  const int w = t >> 6;
  const int mat = blockIdx.x >> 3;            // 0=Q 1=K 2=V
  const int n0 = (blockIdx.x & 7) * 128;
  const int m0 = blockIdx.y * 128;
  const _Float16* B = W3 + (size_t)mat * 1048576;
  const int wm = (w >> 1) * 64;
  const int wn = (w & 1) * 64;
  const int lm = lane & 15;
  const int kq = (lane >> 4) * 8;
  const int srow = lane >> 2;
  const int skof = (lane & 3) * 8;

  f4 acc[4][4];
#pragma unroll
  for (int i = 0; i < 4; i++)
#pragma unroll
    for (int j = 0; j < 4; j++) {
      f4 z = {0.f, 0.f, 0.f, 0.f};
      acc[i][j] = z;
    }

  for (int k0 = 0; k0 < 1024; k0 += 32) {
    __syncthreads();
#pragma unroll
    for (int c = 0; c < 2; c++) {
      int rr = (w + c * 4) * 16 + srow;
      glds16(A + (size_t)(m0 + rr) * 1024 + k0 + skof, (char*)As + (w + c * 4) * 1024);
      glds16(B + (size_t)(n0 + rr) * 1024 + k0 + skof, (char*)Bs + (w + c * 4) * 1024);
    }
    __syncthreads();

    h8 af[4], bf[4];
#pragma unroll
    for (int mt = 0; mt < 4; mt++)
      af[mt] = *(const h8*)(As + (wm + mt * 16 + lm) * 32 + kq);
#pragma unroll
    for (int nt = 0; nt < 4; nt++)
      bf[nt] = *(const h8*)(Bs + (wn + nt * 16 + lm) * 32 + kq);
#pragma unroll
    for (int mt = 0; mt < 4; mt++)
#pragma unroll
      for (int nt = 0; nt < 4; nt++)
        acc[mt][nt] = __builtin_amdgcn_mfma_f32_16x16x32_f16(af[mt], bf[nt],
                                                             acc[mt][nt], 0, 0, 0);
  }

  const float scale = 1.0f / 256.0f;
  const int quad = lane >> 4;
#pragma unroll
  for (int mt = 0; mt < 4; mt++) {
#pragma unroll
    for (int nt = 0; nt < 4; nt++) {
      int n = n0 + wn + nt * 16 + lm;
      int d = n & 63, h = n >> 6;
      int mbase = m0 + wm + mt * 16 + quad * 4;
      int s = mbase & (S_LEN - 1), b = mbase >> 11;
      if (mat == 2) {
        h4 ov = {(_Float16)(acc[mt][nt][0] * scale), (_Float16)(acc[mt][nt][1] * scale),
                 (_Float16)(acc[mt][nt][2] * scale), (_Float16)(acc[mt][nt][3] * scale)};
        *(h4*)&Vto[(((size_t)b * NHEADS + h) * DK + d) * S_LEN + s] = ov;
      } else {
        _Float16* C16 = (mat == 0) ? Qo : Ko;
        int p2 = d & ~1;
#pragma unroll
        for (int r = 0; r < 4; r++) {
          float v = acc[mt][nt][r] * scale;
          float2 sc = *(const float2*)&sc_t[(s + r) * 64 + p2];  // {sin, cos}
          float partner = __shfl_xor(v, 1);
          v = (d & 1) ? fmaf(v, sc.y, partner * sc.x)
                      : fmaf(v, sc.y, -partner * sc.x);
          C16[(((size_t)b * NHEADS + h) * S_LEN + (s + r)) * DK + d] = (_Float16)v;
        }
      }
    }
  }
}

// ---------------- output GEMM: out_f32 = AO * Wo^T -----------------------------
__global__ __launch_bounds__(256) void gemm_out(
    const _Float16* __restrict__ A, const _Float16* __restrict__ B,
    float* __restrict__ C32) {
  __shared__ _Float16 As[128 * 32];
  __shared__ _Float16 Bs[128 * 32];
  const int t = threadIdx.x;
  const int lane = t & 63;
  const int w = t >> 6;
  const int n0 = blockIdx.x * 128;
  const int m0 = blockIdx.y * 128;
  const int wm = (w >> 1) * 64;
  const int wn = (w & 1) * 64;
  const int lm = lane & 15;
  const int kq = (lane >> 4) * 8;
  const int srow = lane >> 2;
  const int skof = (lane & 3) * 8;

  f4 acc[4][4];
#pragma unroll
  for (int i = 0; i < 4; i++)
#pragma unroll
    for (int j = 0; j < 4; j++) {
      f4 z = {0.f, 0.f, 0.f, 0.f};
      acc[i][j] = z;
    }

  for (int k0 = 0; k0 < 1024; k0 += 32) {
    __syncthreads();
#pragma unroll
    for (int c = 0; c < 2; c++) {
      int rr = (w + c * 4) * 16 + srow;
      glds16(A + (size_t)(m0 + rr) * 1024 + k0 + skof, (char*)As + (w + c * 4) * 1024);
      glds16(B + (size_t)(n0 + rr) * 1024 + k0 + skof, (char*)Bs + (w + c * 4) * 1024);
    }
    __syncthreads();

    h8 af[4], bf[4];
#pragma unroll
    for (int mt = 0; mt < 4; mt++)
      af[mt] = *(const h8*)(As + (wm + mt * 16 + lm) * 32 + kq);
#pragma unroll
    for (int nt = 0; nt < 4; nt++)
      bf[nt] = *(const h8*)(Bs + (wn + nt * 16 + lm) * 32 + kq);
#pragma unroll
    for (int mt = 0; mt < 4; mt++)
#pragma unroll
      for (int nt = 0; nt < 4; nt++)
        acc[mt][nt] = __builtin_amdgcn_mfma_f32_16x16x32_f16(af[mt], bf[nt],
                                                             acc[mt][nt], 0, 0, 0);
  }

  const float scale = 1.0f / 256.0f;
  const int quad = lane >> 4;
#pragma unroll
  for (int mt = 0; mt < 4; mt++)
#pragma unroll
    for (int nt = 0; nt < 4; nt++) {
      int n = n0 + wn + nt * 16 + lm;
#pragma unroll
      for (int r = 0; r < 4; r++) {
        int m = m0 + wm + mt * 16 + quad * 4 + r;
        C32[(size_t)m * 1024 + n] = acc[mt][nt][r] * scale;
      }
    }
}

// ---------------- MFMA causal flash attention ----------------------------------
// Q,K: (B*H, S, 64) f16.  Vt: (B*H, 64, S) f16.  O: (B, S, H*64) f16.
// 4 waves, Q-tile 128 (wave owns 32 q-rows), KV-step 64. 2 barriers/step,
// register prefetch of next K/V tile, wave-local P (no 3rd barrier),
// skip-rescale when running max unchanged (alpha == 1 exactly).
__global__ __launch_bounds__(256) void attn_mfma(
    const _Float16* __restrict__ Q, const _Float16* __restrict__ K,
    const _Float16* __restrict__ Vt, _Float16* __restrict__ O) {
  __shared__ _Float16 Ks[64 * 72];   // [s_k][d] stride 72
  __shared__ _Float16 Vs[64 * 72];   // [d][c]  stride 72
  __shared__ _Float16 Ps[128 * 72];  // [s_q][c] stride 72 (wave-local bands)

  const int bh = blockIdx.x;
  const int qt = (gridDim.y - 1) - blockIdx.y;  // heavy tiles dispatch first
  const int q0 = qt * 128;
  const int t = threadIdx.x;
  const int lane = t & 63;
  const int w = t >> 6;
  const int lm = lane & 15;
  const int quad = lane >> 4;
  const size_t qkbase = (size_t)bh * S_LEN * DK;
  const size_t vbase  = (size_t)bh * DK * S_LEN;
  const int srow = t >> 2;
  const int scol = (t & 3) * 16;
  const int wq0 = q0 + w * 32;

  // Q fragments in registers, pre-scaled by 1/sqrt(64)=0.125 (exact in f16)
  h8 qf[2][2];
#pragma unroll
  for (int nt = 0; nt < 2; nt++)
#pragma unroll
    for (int kc = 0; kc < 2; kc++) {
      h8 v = *(const h8*)(Q + qkbase + (size_t)(wq0 + nt * 16 + lm) * DK +
                          kc * 32 + quad * 8);
#pragma unroll
      for (int j = 0; j < 8; j++) v[j] = v[j] * (_Float16)0.125f;
      qf[nt][kc] = v;
    }

  f4 oacc[4][2];
#pragma unroll
  for (int mt = 0; mt < 4; mt++)
#pragma unroll
    for (int nt = 0; nt < 2; nt++) {
      f4 z = {0.f, 0.f, 0.f, 0.f};
      oacc[mt][nt] = z;
    }
  float m_i[2] = {-INFINITY, -INFINITY};
  float l_i[2] = {0.f, 0.f};

  const int ktmax = 2 * qt + 1;
  const _Float16* kg = K + qkbase + (size_t)srow * DK + scol;
  const _Float16* vg = Vt + vbase + (size_t)srow * S_LEN + scol;
  h8 pk0 = *(const h8*)kg;
  h8 pk1 = *(const h8*)(kg + 8);
  h8 pv0 = *(const h8*)vg;
  h8 pv1 = *(const h8*)(vg + 8);

  for (int kt = 0; kt <= ktmax; kt++) {
    __syncthreads();  // barrier A: prior step's frag reads done
    *(h8*)&Ks[srow * 72 + scol] = pk0;
    *(h8*)&Ks[srow * 72 + scol + 8] = pk1;
    *(h8*)&Vs[srow * 72 + scol] = pv0;
    *(h8*)&Vs[srow * 72 + scol + 8] = pv1;
    if (kt < ktmax) {  // prefetch next tile; in flight through compute phase
      const _Float16* kgn = kg + (size_t)(kt + 1) * 64 * DK;
      const _Float16* vgn = vg + (kt + 1) * 64;
      pk0 = *(const h8*)kgn;
      pk1 = *(const h8*)(kgn + 8);
      pv0 = *(const h8*)vgn;
      pv1 = *(const h8*)(vgn + 8);
    }
    __syncthreads();  // barrier B: staging visible

    if (kt * 64 <= wq0 + 31) {  // wave-uniform: skip fully-masked tiles
      // S^T[c][s_q]
      f4 s_[4][2];
#pragma unroll
      for (int mt = 0; mt < 4; mt++)
#pragma unroll
        for (int nt = 0; nt < 2; nt++) {
          f4 z = {0.f, 0.f, 0.f, 0.f};
          s_[mt][nt] = z;
        }
#pragma unroll
      for (int kc = 0; kc < 2; kc++) {
        h8 kf[4];
#pragma unroll
        for (int mt = 0; mt < 4; mt++)
          kf[mt] = *(const h8*)&Ks[(mt * 16 + lm) * 72 + kc * 32 + quad * 8];
#pragma unroll
        for (int mt = 0; mt < 4; mt++)
#pragma unroll
          for (int nt = 0; nt < 2; nt++)
            s_[mt][nt] = __builtin_amdgcn_mfma_f32_16x16x32_f16(kf[mt], qf[nt][kc],
                                                                s_[mt][nt], 0, 0, 0);
      }

      // causal mask (diagonal vicinity only; wave-uniform branch)
      if (kt * 64 + 63 > wq0) {
#pragma unroll
        for (int nt = 0; nt < 2; nt++) {
          int srq = wq0 + nt * 16 + lm;
#pragma unroll
          for (int mt = 0; mt < 4; mt++)
#pragma unroll
            for (int r = 0; r < 4; r++)
              if (kt * 64 + mt * 16 + quad * 4 + r > srq) s_[mt][nt][r] = -INFINITY;
        }
      }

      // online softmax; P -> LDS as f16 (wave-local band, no barrier needed)
#pragma unroll
      for (int nt = 0; nt < 2; nt++) {
        float mx = -INFINITY;
#pragma unroll
        for (int mt = 0; mt < 4; mt++)
#pragma unroll
          for (int r = 0; r < 4; r++) mx = fmaxf(mx, s_[mt][nt][r]);
        mx = fmaxf(mx, __shfl_xor(mx, 16));
        mx = fmaxf(mx, __shfl_xor(mx, 32));
        const bool grow = __any(mx > m_i[nt]);
        const float mnew = grow ? fmaxf(m_i[nt], mx) : m_i[nt];
        float sum = 0.f;
#pragma unroll
        for (int mt = 0; mt < 4; mt++) {
          float p0 = __expf(s_[mt][nt][0] - mnew);
          float p1 = __expf(s_[mt][nt][1] - mnew);
          float p2 = __expf(s_[mt][nt][2] - mnew);
          float p3 = __expf(s_[mt][nt][3] - mnew);
          sum += (p0 + p1) + (p2 + p3);
          h4 pv = {(_Float16)p0, (_Float16)p1, (_Float16)p2, (_Float16)p3};
          *(h4*)&Ps[(w * 32 + nt * 16 + lm) * 72 + mt * 16 + quad * 4] = pv;
        }
        sum += __shfl_xor(sum, 16);
        sum += __shfl_xor(sum, 32);
        if (grow) {
          float alpha = __expf(m_i[nt] - mnew);
          m_i[nt] = mnew;
          l_i[nt] = fmaf(l_i[nt], alpha, sum);
#pragma unroll
          for (int mt = 0; mt < 4; mt++) {
            oacc[mt][nt][0] *= alpha; oacc[mt][nt][1] *= alpha;
            oacc[mt][nt][2] *= alpha; oacc[mt][nt][3] *= alpha;
          }
        } else {
          l_i[nt] += sum;
        }
      }

      // O^T += Vt_tile * P^T (P produced by this wave; in-order DS per wave)
#pragma unroll
      for (int kc = 0; kc < 2; kc++) {
        h8 vf[4], pf[2];
#pragma unroll
        for (int mt = 0; mt < 4; mt++)
          vf[mt] = *(const h8*)&Vs[(mt * 16 + lm) * 72 + kc * 32 + quad * 8];
#pragma unroll
        for (int nt = 0; nt < 2; nt++)
          pf[nt] = *(const h8*)&Ps[(w * 32 + nt * 16 + lm) * 72 + kc * 32 + quad * 8];
#pragma unroll
        for (int mt = 0; mt < 4; mt++)
#pragma unroll
          for (int nt = 0; nt < 2; nt++)
            oacc[mt][nt] = __builtin_amdgcn_mfma_f32_16x16x32_f16(vf[mt], pf[nt],
                                                                  oacc[mt][nt], 0, 0, 0);
      }
    }
  }

  // normalize + store O^T tiles: col = s_q (lane), rows = 4 consecutive d -> h4
  const int b = bh >> 4, head = bh & 15;
#pragma unroll
  for (int nt = 0; nt < 2; nt++) {
    float inv = 1.0f / l_i[nt];
    int s = wq0 + nt * 16 + lm;
#pragma unroll
    for (int mt = 0; mt < 4; mt++) {
      h4 ov = {(_Float16)(oacc[mt][nt][0] * inv), (_Float16)(oacc[mt][nt][1] * inv),
               (_Float16)(oacc[mt][nt][2] * inv), (_Float16)(oacc[mt][nt][3] * inv)};
      *(h4*)&O[((size_t)b * S_LEN + s) * 1024 + head * 64 + mt * 16 + quad * 4] = ov;
    }
  }
}

extern "C" void kernel_launch(void* const* d_in, const int* in_sizes, int n_in,
                              void* d_out, int out_size, void* d_ws, size_t ws_size,
                              hipStream_t stream) {
  const float* x   = (const float*)d_in[0];
  const int*   pos = (const int*)d_in[1];
  const float* Wq  = (const float*)d_in[2];
  const float* Wk  = (const float*)d_in[3];
  const float* Wv  = (const float*)d_in[4];
  const float* Wo  = (const float*)d_in[5];
  float* out = (float*)d_out;
  (void)in_sizes; (void)n_in; (void)out_size; (void)ws_size;

  const size_t NT = (size_t)4 * S_LEN * 1024;
  _Float16* q16  = (_Float16*)d_ws;
  _Float16* k16  = q16 + NT;
  _Float16* vt16 = k16 + NT;
  _Float16* aoh  = vt16 + NT;
  _Float16* xh   = aoh + NT;
  _Float16* wh   = xh + NT;                    // 4 x 1048576
  float* sc_t = (float*)(wh + 4 * 1048576);    // 2048 x 64 interleaved sin/cos

  rope_table_kernel<<<256, 256, 0, stream>>>(pos, sc_t);
  cvt_all<<<12288, 256, 0, stream>>>(x, Wq, Wk, Wv, Wo, xh, wh);

  gemm_qkv<<<dim3(24, 64), 256, 0, stream>>>(xh, wh, q16, k16, vt16, sc_t);

  attn_mfma<<<dim3(64, S_LEN / 128), 256, 0, stream>>>(q16, k16, vt16, aoh);

  gemm_out<<<dim3(8, 64), 256, 0, stream>>>(aoh, wh + 3145728, out);
}